// Round 4
// baseline (4562.795 us; speedup 1.0000x reference)
//
#include <hip/hip_runtime.h>

__device__ __forceinline__ float lrelu(float x) { return x >= 0.f ? x : 0.2f * x; }

// ---------------------------------------------------------------------------
// conv0 (half of output channels per pass): fp32 x (8,3,256,256),
// w (64,3,3,3), s1 p1, +bias +lrelu -> ACTIVATED fp32 (8,32,256,256)
// cogBase selects which 32 output channels this pass computes.
// ---------------------------------------------------------------------------
__global__ __launch_bounds__(256) void conv0_k(const float* __restrict__ x,
                                               const float* __restrict__ w,
                                               const float* __restrict__ bias,
                                               float* __restrict__ out,
                                               int cogBase) {
    __shared__ float sIn[3][34][34];
    __shared__ float sW[27][16];
    const int H = 256;
    int tid = threadIdx.x, tx = tid & 31, ty = tid >> 5;
    int tX = (blockIdx.x & 7) * 32, tY = (blockIdx.x >> 3) * 32;
    int b = blockIdx.y, cogL = blockIdx.z * 16;         // local channel group (0/16)
    int cogG = cogBase + cogL;                           // global cout base
    float acc[4][16] = {};
    const float* inB = x + (size_t)b * 3 * H * H;
    for (int idx = tid; idx < 3 * 1156; idx += 256) {
        int ci = idx / 1156, r = idx % 1156, iy = r / 34, ix = r % 34;
        int gy = tY - 1 + iy, gx = tX - 1 + ix;
        float v = 0.f;
        if ((unsigned)gy < 256u && (unsigned)gx < 256u)
            v = inB[(ci * H + gy) * H + gx];
        sIn[ci][iy][ix] = v;
    }
    for (int idx = tid; idx < 27 * 16; idx += 256) {
        int co = idx & 15, rest = idx >> 4;
        sW[rest][co] = w[(cogG + co) * 27 + rest];
    }
    __syncthreads();
#pragma unroll
    for (int ci = 0; ci < 3; ci++)
#pragma unroll
        for (int dy = 0; dy < 3; dy++)
#pragma unroll
            for (int dx = 0; dx < 3; dx++) {
                float a0 = sIn[ci][ty + dy][tx + dx];
                float a1 = sIn[ci][ty + 8 + dy][tx + dx];
                float a2 = sIn[ci][ty + 16 + dy][tx + dx];
                float a3 = sIn[ci][ty + 24 + dy][tx + dx];
                const float* wp = sW[ci * 9 + dy * 3 + dx];
#pragma unroll
                for (int co = 0; co < 16; co++) {
                    float wv = wp[co];
                    acc[0][co] += a0 * wv; acc[1][co] += a1 * wv;
                    acc[2][co] += a2 * wv; acc[3][co] += a3 * wv;
                }
            }
    float* outB = out + ((size_t)b * 32 + cogL) * H * H;
#pragma unroll
    for (int co = 0; co < 16; co++) {
        float bv = bias[cogG + co];
#pragma unroll
        for (int r = 0; r < 4; r++)
            outB[(co * H + (tY + ty + 8 * r)) * H + tX + tx] =
                lrelu(acc[r][co] + bv);
    }
}

// ---------------------------------------------------------------------------
// generic 3x3 s1 p1 conv, fp32 raw input + per-channel (scale,shift)+lrelu,
// fp32 weights. Cin % 4 == 0, Cout % 16 == 0; writes RAW fp32.
// ---------------------------------------------------------------------------
__global__ __launch_bounds__(256) void conv3x3_k(const float* __restrict__ in,
                                                 const float* __restrict__ w,
                                                 const float2* __restrict__ ss,
                                                 float* __restrict__ out,
                                                 int Cin, int Cout, int H) {
    __shared__ float sIn[4][34][34];
    __shared__ float sW[36][16];
    int tid = threadIdx.x, tx = tid & 31, ty = tid >> 5;
    int tpr = H >> 5;
    int tX = (blockIdx.x % tpr) * 32, tY = (blockIdx.x / tpr) * 32;
    int b = blockIdx.y, cog = blockIdx.z * 16;
    float acc[4][16] = {};
    const float* inB = in + (size_t)b * Cin * H * H;
    for (int c0 = 0; c0 < Cin; c0 += 4) {
        __syncthreads();
        for (int idx = tid; idx < 4 * 1156; idx += 256) {
            int ci = idx / 1156, r = idx % 1156, iy = r / 34, ix = r % 34;
            int gy = tY - 1 + iy, gx = tX - 1 + ix;
            float v = 0.f;
            if ((unsigned)gy < (unsigned)H && (unsigned)gx < (unsigned)H) {
                float2 t = ss[c0 + ci];
                v = lrelu(t.x * inB[((c0 + ci) * H + gy) * H + gx] + t.y);
            }
            sIn[ci][iy][ix] = v;
        }
        for (int idx = tid; idx < 4 * 9 * 16; idx += 256) {
            int co = idx & 15, rest = idx >> 4;
            sW[rest][co] = w[(cog + co) * Cin * 9 + c0 * 9 + rest];
        }
        __syncthreads();
#pragma unroll
        for (int ci = 0; ci < 4; ci++)
#pragma unroll
            for (int dy = 0; dy < 3; dy++)
#pragma unroll
                for (int dx = 0; dx < 3; dx++) {
                    float a0 = sIn[ci][ty + dy][tx + dx];
                    float a1 = sIn[ci][ty + 8 + dy][tx + dx];
                    float a2 = sIn[ci][ty + 16 + dy][tx + dx];
                    float a3 = sIn[ci][ty + 24 + dy][tx + dx];
                    const float* wp = sW[ci * 9 + dy * 3 + dx];
#pragma unroll
                    for (int co = 0; co < 16; co++) {
                        float wv = wp[co];
                        acc[0][co] += a0 * wv; acc[1][co] += a1 * wv;
                        acc[2][co] += a2 * wv; acc[3][co] += a3 * wv;
                    }
                }
    }
    float* outB = out + ((size_t)b * Cout + cog) * H * H;
#pragma unroll
    for (int co = 0; co < 16; co++)
#pragma unroll
        for (int r = 0; r < 4; r++)
            outB[(co * H + (tY + ty + 8 * r)) * H + tX + tx] = acc[r][co];
}

// ---------------------------------------------------------------------------
// generic 4x4 stride-2 pad-1 conv, fp32.
// XFORM: apply lrelu(scale*x+shift) on load; else input already activated.
// ACCUM: out += (partial-cin pass 2). Cin covered this pass; CinTot/cinBase
// address the weight tensor. Writes RAW fp32. Cin%2==0, Cout%16==0.
// ---------------------------------------------------------------------------
template <bool XFORM, bool ACCUM>
__global__ __launch_bounds__(256) void conv4x4_k(const float* __restrict__ in,
                                                 const float* __restrict__ w,
                                                 const float2* __restrict__ ss,
                                                 float* __restrict__ out,
                                                 int Cin, int CinTot, int cinBase,
                                                 int Cout, int Hin) {
    __shared__ float sIn[2][4356];   // 66*66
    __shared__ float sW[32][16];
    int Hout = Hin >> 1;
    int tid = threadIdx.x, tx = tid & 31, ty = tid >> 5;
    int tpr = Hout >> 5;
    int tX = (blockIdx.x % tpr) * 32, tY = (blockIdx.x / tpr) * 32;
    int b = blockIdx.y, cog = blockIdx.z * 16;
    int oy = 2 * tY - 1, ox = 2 * tX - 1;
    float acc[4][16] = {};
    const float* inB = in + (size_t)b * Cin * Hin * Hin;
    for (int c0 = 0; c0 < Cin; c0 += 2) {
        __syncthreads();
        for (int idx = tid; idx < 2 * 4356; idx += 256) {
            int ci = idx / 4356, r = idx % 4356, iy = r / 66, ix = r % 66;
            int gy = oy + iy, gx = ox + ix;
            float v = 0.f;
            if ((unsigned)gy < (unsigned)Hin && (unsigned)gx < (unsigned)Hin) {
                float f = inB[((c0 + ci) * Hin + gy) * Hin + gx];
                if (XFORM) {
                    float2 t = ss[cinBase + c0 + ci];
                    v = lrelu(t.x * f + t.y);
                } else {
                    v = f;
                }
            }
            sIn[ci][r] = v;
        }
        for (int idx = tid; idx < 2 * 16 * 16; idx += 256) {
            int co = idx & 15, rest = idx >> 4;   // rest = ci*16 + k
            sW[rest][co] = w[(cog + co) * CinTot * 16 + (cinBase + c0) * 16 + rest];
        }
        __syncthreads();
#pragma unroll
        for (int ci = 0; ci < 2; ci++)
#pragma unroll
            for (int dy = 0; dy < 4; dy++)
#pragma unroll
                for (int dx = 0; dx < 4; dx++) {
                    float a0 = sIn[ci][(2 * ty + dy) * 66 + 2 * tx + dx];
                    float a1 = sIn[ci][(2 * (ty + 8) + dy) * 66 + 2 * tx + dx];
                    float a2 = sIn[ci][(2 * (ty + 16) + dy) * 66 + 2 * tx + dx];
                    float a3 = sIn[ci][(2 * (ty + 24) + dy) * 66 + 2 * tx + dx];
                    const float* wp = sW[ci * 16 + dy * 4 + dx];
#pragma unroll
                    for (int co = 0; co < 16; co++) {
                        float wv = wp[co];
                        acc[0][co] += a0 * wv; acc[1][co] += a1 * wv;
                        acc[2][co] += a2 * wv; acc[3][co] += a3 * wv;
                    }
                }
    }
    float* outB = out + ((size_t)b * Cout + cog) * Hout * Hout;
#pragma unroll
    for (int co = 0; co < 16; co++)
#pragma unroll
        for (int r = 0; r < 4; r++) {
            size_t o = (size_t)(co * Hout + (tY + ty + 8 * r)) * Hout + tX + tx;
            if (ACCUM) outB[o] += acc[r][co]; else outB[o] = acc[r][co];
        }
}

// ---------------------------------------------------------------------------
// BN batch stats: per channel partial (sum, sumsq) in FP64 over B=8 x HW
// ---------------------------------------------------------------------------
__global__ __launch_bounds__(256) void stats_k(const float* __restrict__ x,
                                               double2* __restrict__ part,
                                               int C, int hwShift) {
    int c = blockIdx.y, s = blockIdx.x, S = gridDim.x;
    int HW = 1 << hwShift;
    int total = 8 << hwShift;
    int per = total / S;
    int lo = s * per;
    double sum = 0.0, sq = 0.0;
    for (int i = lo + threadIdx.x; i < lo + per; i += 256) {
        int b = i >> hwShift, p = i & (HW - 1);
        double v = (double)x[((size_t)(b * C + c) << hwShift) + p];
        sum += v; sq += v * v;
    }
    __shared__ double s1[256], s2[256];
    s1[threadIdx.x] = sum; s2[threadIdx.x] = sq;
    __syncthreads();
    for (int o = 128; o; o >>= 1) {
        if (threadIdx.x < o) {
            s1[threadIdx.x] += s1[threadIdx.x + o];
            s2[threadIdx.x] += s2[threadIdx.x + o];
        }
        __syncthreads();
    }
    if (threadIdx.x == 0) { part[c * S + s].x = s1[0]; part[c * S + s].y = s2[0]; }
}

__global__ void bnfin_k(const double2* __restrict__ part, int S, int C, double invN,
                        const float* __restrict__ g, const float* __restrict__ bb,
                        float2* __restrict__ ss) {
    int c = threadIdx.x;
    if (c >= C) return;
    double sum = 0.0, sq = 0.0;
    for (int s = 0; s < S; s++) { double2 p = part[c * S + s]; sum += p.x; sq += p.y; }
    double m = sum * invN;
    double v = sq * invN - m * m;
    double sc = (double)g[c] / sqrt(v + 1e-5);
    ss[c] = make_float2((float)sc, (float)((double)bb[c] - m * sc));
}

// ---------------------------------------------------------------------------
// h6raw (8,256,64,64) + BN6 transform+lrelu -> tok (8,4096,256) fp32
// ---------------------------------------------------------------------------
__global__ __launch_bounds__(256) void transp_k(const float* __restrict__ h6,
                                                const float2* __restrict__ ss,
                                                float* __restrict__ tok) {
    __shared__ float sT[32][33];
    int tx = threadIdx.x & 31, ty = threadIdx.x >> 5;
    int n0 = blockIdx.x * 32, d0 = blockIdx.y * 32, b = blockIdx.z;
    const float* hb = h6 + ((size_t)b * 256 + d0) * 4096 + n0;
#pragma unroll
    for (int r = 0; r < 4; r++) {
        int d = ty + 8 * r;
        float2 t = ss[d0 + d];
        sT[d][tx] = lrelu(t.x * hb[d * 4096 + tx] + t.y);
    }
    __syncthreads();
    float* tb = tok + ((size_t)b * 4096 + n0) * 256 + d0;
#pragma unroll
    for (int r = 0; r < 4; r++) {
        int n = ty + 8 * r;
        tb[n * 256 + tx] = sT[tx][n];
    }
}

// ---------------------------------------------------------------------------
// Token stage: gating argmax (softmax monotone), selected-expert body slice,
// ortho, shared cls MLP. One wave per token, 4 waves/block. All fp32.
// ---------------------------------------------------------------------------
__global__ __launch_bounds__(256) void token_k(const float* __restrict__ tok,
                                               const float* __restrict__ wg,   // (256,12)
                                               const float* __restrict__ bw,   // (256,3072)
                                               const float* __restrict__ bb,   // (3072)
                                               const float* __restrict__ ow,   // (3072)
                                               const float* __restrict__ w1,   // (256,32)
                                               const float* __restrict__ b1,   // (32)
                                               const float* __restrict__ w2,   // (32)
                                               const float* __restrict__ b2,   // (1)
                                               float* __restrict__ outp) {
    __shared__ float sf[4][256];
    const int tid = threadIdx.x, wave = tid >> 6, l = tid & 63;
    const int t = blockIdx.x * 4 + wave;
    const float4 tv = reinterpret_cast<const float4*>(tok + (size_t)t * 256)[l];
    sf[wave][4 * l + 0] = tv.x; sf[wave][4 * l + 1] = tv.y;
    sf[wave][4 * l + 2] = tv.z; sf[wave][4 * l + 3] = tv.w;

    // gating logits (argmax only; softmax is monotone, first-max tiebreak)
    float lg[12];
#pragma unroll
    for (int e = 0; e < 12; e++) lg[e] = 0.f;
    const float tj[4] = {tv.x, tv.y, tv.z, tv.w};
#pragma unroll
    for (int j = 0; j < 4; j++) {
        const float* wr = wg + (4 * l + j) * 12;
#pragma unroll
        for (int e = 0; e < 12; e++) lg[e] += tj[j] * wr[e];
    }
#pragma unroll
    for (int off = 32; off > 0; off >>= 1) {
#pragma unroll
        for (int e = 0; e < 12; e++) lg[e] += __shfl_xor(lg[e], off);
    }
    int idx = 0; float best = lg[0];
#pragma unroll
    for (int e = 1; e < 12; e++)
        if (lg[e] > best) { best = lg[e]; idx = e; }
    const int cb = idx * 256;

    // body slice for the selected expert: f[4l..4l+3]
    float f0 = 0.f, f1 = 0.f, f2 = 0.f, f3 = 0.f;
    const float* bwp = bw + cb + 4 * l;
#pragma unroll 4
    for (int d = 0; d < 256; d++) {
        const float td = sf[wave][d];
        const float4 wv = *reinterpret_cast<const float4*>(bwp + (size_t)d * 3072);
        f0 += td * wv.x; f1 += td * wv.y;
        f2 += td * wv.z; f3 += td * wv.w;
    }
    float fj[4] = {f0, f1, f2, f3};
#pragma unroll
    for (int j = 0; j < 4; j++) {
        int jj = cb + 4 * l + j;
        float v = lrelu(fj[j] + bb[jj]);
        v = lrelu(v * ow[jj]);
        sf[wave][4 * l + j] = v;
    }

    // cls MLP: 256 -> 32 (lanes 0..31) -> 1
    float o = 0.f;
    if (l < 32) {
        float h = b1[l];
#pragma unroll 4
        for (int j = 0; j < 256; j++) h += sf[wave][j] * w1[j * 32 + l];
        h = lrelu(h);
        o = h * w2[l];
    }
    o += __shfl_xor(o, 16); o += __shfl_xor(o, 8); o += __shfl_xor(o, 4);
    o += __shfl_xor(o, 2);  o += __shfl_xor(o, 1);
    if (l == 0) outp[t] = o + b2[0];
}

// ---------------------------------------------------------------------------
extern "C" void kernel_launch(void* const* d_in, const int* in_sizes, int n_in,
                              void* d_out, int out_size, void* d_ws, size_t ws_size,
                              hipStream_t stream) {
    const float* x   = (const float*)d_in[0];
    const float* w0  = (const float*)d_in[1];
    const float* b0  = (const float*)d_in[2];
    const float* w1  = (const float*)d_in[3];
    const float* g1  = (const float*)d_in[4];
    const float* be1 = (const float*)d_in[5];
    const float* w2  = (const float*)d_in[6];
    const float* g2  = (const float*)d_in[7];
    const float* be2 = (const float*)d_in[8];
    const float* w3  = (const float*)d_in[9];
    const float* g3  = (const float*)d_in[10];
    const float* be3 = (const float*)d_in[11];
    const float* w4  = (const float*)d_in[12];
    const float* g4  = (const float*)d_in[13];
    const float* be4 = (const float*)d_in[14];
    const float* w5  = (const float*)d_in[15];
    const float* g5  = (const float*)d_in[16];
    const float* be5 = (const float*)d_in[17];
    const float* w6  = (const float*)d_in[18];
    const float* g6  = (const float*)d_in[19];
    const float* be6 = (const float*)d_in[20];
    const float* wg  = (const float*)d_in[21];
    const float* bw  = (const float*)d_in[22];
    const float* bbp = (const float*)d_in[23];
    const float* owp = (const float*)d_in[24];
    const float* cw1 = (const float*)d_in[25];
    const float* cb1 = (const float*)d_in[26];
    const float* cw2 = (const float*)d_in[27];
    const float* cb2 = (const float*)d_in[28];

    char* W = (char*)d_ws;
    // small region [0, 256KiB): ss tables + fp64 stats partials
    float2* ssb = (float2*)W;
    float2* ss1 = ssb;          // 64
    float2* ss2 = ssb + 64;     // 128
    float2* ss3 = ssb + 192;    // 128
    float2* ss4 = ssb + 320;    // 256
    float2* ss5 = ssb + 576;    // 256
    float2* ss6 = ssb + 832;    // 256
    double2* part = (double2*)(W + 16384);  // up to 256*32*16B = 128KiB

    // big regions: A = 64MiB @256KiB, B = 32MiB after A. Peak ~96.3MiB
    // (same footprint class R2 ran without faulting).
    char* A = W + 262144;
    char* B = A + 67108864;
    float* h0  = (float*)A;              // (8,32,256,256) fp32 ACTIVATED (per pass)
    float* h1  = (float*)B;              // (8,64,128,128) raw = 32MiB
    float* h2  = (float*)A;              // (8,128,128,128) raw = 64MiB (h0 dead)
    float* h3  = (float*)B;              // (8,128,64,64) raw = 16MiB (h1 dead)
    float* h4  = (float*)A;              // (8,256,64,64) raw, A[0..32MiB) (h2 dead)
    float* h5  = (float*)(A + 33554432); // (8,256,64,64) raw, A[32..64MiB)
    float* h6  = (float*)B;              // (8,256,64,64) raw (h3 dead)
    float* tok = (float*)A;              // (8,4096,256) fp32, A[0..32MiB) (h4 dead)

    // conv0+conv1 in two cin-halves (keeps h0 fp32 within 64MiB)
    conv0_k<<<dim3(64, 8, 2), 256, 0, stream>>>(x, w0, b0, h0, 0);
    conv4x4_k<false, false><<<dim3(16, 8, 4), 256, 0, stream>>>(
        h0, w1, nullptr, h1, 32, 64, 0, 64, 256);
    conv0_k<<<dim3(64, 8, 2), 256, 0, stream>>>(x, w0, b0, h0, 32);
    conv4x4_k<false, true><<<dim3(16, 8, 4), 256, 0, stream>>>(
        h0, w1, nullptr, h1, 32, 64, 32, 64, 256);
    stats_k<<<dim3(32, 64), 256, 0, stream>>>(h1, part, 64, 14);
    bnfin_k<<<1, 256, 0, stream>>>(part, 32, 64, 1.0 / 131072.0, g1, be1, ss1);
    // conv2 3x3: h1 (+bn1+lrelu) -> h2 raw
    conv3x3_k<<<dim3(16, 8, 8), 256, 0, stream>>>(h1, w2, ss1, h2, 64, 128, 128);
    stats_k<<<dim3(32, 128), 256, 0, stream>>>(h2, part, 128, 14);
    bnfin_k<<<1, 256, 0, stream>>>(part, 32, 128, 1.0 / 131072.0, g2, be2, ss2);
    // conv3 4x4 s2: h2 (+bn2+lrelu) -> h3 raw
    conv4x4_k<true, false><<<dim3(4, 8, 8), 256, 0, stream>>>(
        h2, w3, ss2, h3, 128, 128, 0, 128, 128);
    stats_k<<<dim3(32, 128), 256, 0, stream>>>(h3, part, 128, 12);
    bnfin_k<<<1, 256, 0, stream>>>(part, 32, 128, 1.0 / 32768.0, g3, be3, ss3);
    // conv4 3x3: h3 (+bn3+lrelu) -> h4 raw
    conv3x3_k<<<dim3(4, 8, 16), 256, 0, stream>>>(h3, w4, ss3, h4, 128, 256, 64);
    stats_k<<<dim3(32, 256), 256, 0, stream>>>(h4, part, 256, 12);
    bnfin_k<<<1, 256, 0, stream>>>(part, 32, 256, 1.0 / 32768.0, g4, be4, ss4);
    // conv5 3x3: h4 (+bn4+lrelu) -> h5 raw
    conv3x3_k<<<dim3(4, 8, 16), 256, 0, stream>>>(h4, w5, ss4, h5, 256, 256, 64);
    stats_k<<<dim3(32, 256), 256, 0, stream>>>(h5, part, 256, 12);
    bnfin_k<<<1, 256, 0, stream>>>(part, 32, 256, 1.0 / 32768.0, g5, be5, ss5);
    // conv6 3x3: h5 (+bn5+lrelu) -> h6 raw
    conv3x3_k<<<dim3(4, 8, 16), 256, 0, stream>>>(h5, w6, ss5, h6, 256, 256, 64);
    stats_k<<<dim3(32, 256), 256, 0, stream>>>(h6, part, 256, 12);
    bnfin_k<<<1, 256, 0, stream>>>(part, 32, 256, 1.0 / 32768.0, g6, be6, ss6);
    // transpose + BN6 + lrelu -> tok (8,4096,256)
    transp_k<<<dim3(128, 8, 8), 256, 0, stream>>>(h6, ss6, tok);
    // token stage -> out fp32 (8,4096,1)
    token_k<<<8192, 256, 0, stream>>>(tok, wg, bw, bbp, owp, cw1, cb1, cw2, cb2,
                                      (float*)d_out);
}

// Round 5
// 4254.679 us; speedup vs baseline: 1.0724x; 1.0724x over previous
//
#include <hip/hip_runtime.h>

__device__ __forceinline__ float lrelu(float x) { return x >= 0.f ? x : 0.2f * x; }

// ---------------------------------------------------------------------------
// conv0 (half of output channels per pass): fp32 x (8,3,256,256),
// w (64,3,3,3), s1 p1, +bias +lrelu -> ACTIVATED fp32 (8,32,256,256)
// ---------------------------------------------------------------------------
__global__ __launch_bounds__(256) void conv0_k(const float* __restrict__ x,
                                               const float* __restrict__ w,
                                               const float* __restrict__ bias,
                                               float* __restrict__ out,
                                               int cogBase) {
    __shared__ float sIn[3][34][34];
    __shared__ float sW[27][16];
    const int H = 256;
    int tid = threadIdx.x, tx = tid & 31, ty = tid >> 5;
    int tX = (blockIdx.x & 7) * 32, tY = (blockIdx.x >> 3) * 32;
    int b = blockIdx.y, cogL = blockIdx.z * 16;
    int cogG = cogBase + cogL;
    float acc[4][16] = {};
    const float* inB = x + (size_t)b * 3 * H * H;
    for (int idx = tid; idx < 3 * 1156; idx += 256) {
        int ci = idx / 1156, r = idx % 1156, iy = r / 34, ix = r % 34;
        int gy = tY - 1 + iy, gx = tX - 1 + ix;
        float v = 0.f;
        if ((unsigned)gy < 256u && (unsigned)gx < 256u)
            v = inB[(ci * H + gy) * H + gx];
        sIn[ci][iy][ix] = v;
    }
    for (int idx = tid; idx < 27 * 16; idx += 256) {
        int co = idx & 15, rest = idx >> 4;
        sW[rest][co] = w[(cogG + co) * 27 + rest];
    }
    __syncthreads();
#pragma unroll
    for (int ci = 0; ci < 3; ci++)
#pragma unroll
        for (int dy = 0; dy < 3; dy++)
#pragma unroll
            for (int dx = 0; dx < 3; dx++) {
                float a0 = sIn[ci][ty + dy][tx + dx];
                float a1 = sIn[ci][ty + 8 + dy][tx + dx];
                float a2 = sIn[ci][ty + 16 + dy][tx + dx];
                float a3 = sIn[ci][ty + 24 + dy][tx + dx];
                const float* wp = sW[ci * 9 + dy * 3 + dx];
#pragma unroll
                for (int co = 0; co < 16; co++) {
                    float wv = wp[co];
                    acc[0][co] += a0 * wv; acc[1][co] += a1 * wv;
                    acc[2][co] += a2 * wv; acc[3][co] += a3 * wv;
                }
            }
    float* outB = out + ((size_t)b * 32 + cogL) * H * H;
#pragma unroll
    for (int co = 0; co < 16; co++) {
        float bv = bias[cogG + co];
#pragma unroll
        for (int r = 0; r < 4; r++)
            outB[(co * H + (tY + ty + 8 * r)) * H + tX + tx] =
                lrelu(acc[r][co] + bv);
    }
}

// ---------------------------------------------------------------------------
// 3x3 s1 p1 conv, software-pipelined (double-buffered LDS, 1 barrier/step).
// Input raw fp32 + per-channel (scale,shift)+lrelu on staging. cin-step 2.
// COG = output channels per block. Writes RAW fp32.
// ---------------------------------------------------------------------------
template <int COG>
__global__ __launch_bounds__(256) void conv3x3_k(const float* __restrict__ in,
                                                 const float* __restrict__ w,
                                                 const float2* __restrict__ ss,
                                                 float* __restrict__ out,
                                                 int Cin, int Cout, int H) {
    __shared__ float sInF[2 * 2312];            // 2 bufs x 2 cins x 34x34
    __shared__ float sWF[2 * 18 * COG];
    const int tid = threadIdx.x, tx = tid & 31, ty = tid >> 5;
    const int tpr = H >> 5;
    const int tX = (blockIdx.x % tpr) * 32, tY = (blockIdx.x / tpr) * 32;
    const int b = blockIdx.y, cog = blockIdx.z * COG;
    const int HH = H * H;
    const float* inB = in + (size_t)b * Cin * HH;

    constexpr int NS = 10;                       // ceil(2312/256)
    int soff[NS]; float fm[NS]; int cis[NS];
#pragma unroll
    for (int r = 0; r < NS; r++) {
        int idx = tid + r * 256;
        int ci = idx / 1156, rem = idx % 1156;
        int iy = rem / 34, ix = rem % 34;
        int gy = tY - 1 + iy, gx = tX - 1 + ix;
        bool ok = (idx < 2312) && ((unsigned)gy < (unsigned)H) &&
                  ((unsigned)gx < (unsigned)H);
        soff[r] = ok ? (ci * HH + gy * H + gx) : 0;
        fm[r] = ok ? 1.f : 0.f;
        cis[r] = ci;
    }
    constexpr int NW = (18 * COG + 255) / 256;
    int wgo[NW];
#pragma unroll
    for (int r = 0; r < NW; r++) {
        int widx = tid + r * 256;
        int co = widx % COG, rest = widx / COG;  // rest = ci*9 + t
        int ciw = rest / 9, t = rest % 9;
        wgo[r] = ((cog + co) * Cin + ciw) * 9 + t;
    }

    float acc[4][COG];
#pragma unroll
    for (int r = 0; r < 4; r++)
#pragma unroll
        for (int c = 0; c < COG; c++) acc[r][c] = 0.f;

    const int steps = Cin >> 1;

    {   // stage step 0 -> buf 0
        float pf[NS]; float pw[NW];
        float2 t0 = ss[0], t1 = ss[1];
#pragma unroll
        for (int r = 0; r < NS; r++) pf[r] = inB[soff[r]];
#pragma unroll
        for (int r = 0; r < NW; r++)
            pw[r] = (tid + r * 256 < 18 * COG) ? w[wgo[r]] : 0.f;
#pragma unroll
        for (int r = 0; r < NS; r++)
            if (tid + r * 256 < 2312) {
                float2 t = cis[r] ? t1 : t0;
                float v = t.x * pf[r] + t.y;
                v = (v >= 0.f ? v : 0.2f * v) * fm[r];
                sInF[tid + r * 256] = v;
            }
#pragma unroll
        for (int r = 0; r < NW; r++)
            if (tid + r * 256 < 18 * COG) sWF[tid + r * 256] = pw[r];
    }
    __syncthreads();

    for (int k = 0; k < steps; k++) {
        const int cur = k & 1;
        const bool more = (k + 1) < steps;
        float pf[NS]; float pw[NW]; float2 t0, t1;
        if (more) {
            const int c0n = (k + 1) * 2;
            const float* p = inB + (size_t)c0n * HH;
            t0 = ss[c0n]; t1 = ss[c0n + 1];
#pragma unroll
            for (int r = 0; r < NS; r++) pf[r] = p[soff[r]];
#pragma unroll
            for (int r = 0; r < NW; r++)
                pw[r] = (tid + r * 256 < 18 * COG) ? w[wgo[r] + c0n * 9] : 0.f;
        }
        const float* sI = sInF + cur * 2312;
        const float* sw = sWF + cur * 18 * COG;
#pragma unroll
        for (int ci = 0; ci < 2; ci++)
#pragma unroll
            for (int dy = 0; dy < 3; dy++)
#pragma unroll
                for (int dx = 0; dx < 3; dx++) {
                    const float* rowp = sI + ci * 1156 + (ty + dy) * 34 + tx + dx;
                    float a0 = rowp[0];
                    float a1 = rowp[8 * 34];
                    float a2 = rowp[16 * 34];
                    float a3 = rowp[24 * 34];
                    const float* wp = sw + (ci * 9 + dy * 3 + dx) * COG;
#pragma unroll
                    for (int c = 0; c < COG; c++) {
                        float wv = wp[c];
                        acc[0][c] += a0 * wv; acc[1][c] += a1 * wv;
                        acc[2][c] += a2 * wv; acc[3][c] += a3 * wv;
                    }
                }
        if (more) {
            const int nb = (cur ^ 1);
#pragma unroll
            for (int r = 0; r < NS; r++)
                if (tid + r * 256 < 2312) {
                    float2 t = cis[r] ? t1 : t0;
                    float v = t.x * pf[r] + t.y;
                    v = (v >= 0.f ? v : 0.2f * v) * fm[r];
                    sInF[nb * 2312 + tid + r * 256] = v;
                }
#pragma unroll
            for (int r = 0; r < NW; r++)
                if (tid + r * 256 < 18 * COG)
                    sWF[nb * 18 * COG + tid + r * 256] = pw[r];
        }
        __syncthreads();
    }

    float* outB = out + ((size_t)b * Cout + cog) * HH;
#pragma unroll
    for (int c = 0; c < COG; c++)
#pragma unroll
        for (int r = 0; r < 4; r++)
            outB[(c * H + (tY + ty + 8 * r)) * H + tX + tx] = acc[r][c];
}

// ---------------------------------------------------------------------------
// 4x4 stride-2 pad-1 conv, software-pipelined, cin-step 1.
// XFORM: lrelu(scale*x+shift) on staging; else input already activated.
// Cin = channels this pass; CinTot/cinBase address weights; accum adds.
// ---------------------------------------------------------------------------
template <int COG, bool XFORM>
__global__ __launch_bounds__(256) void conv4x4_k(const float* __restrict__ in,
                                                 const float* __restrict__ w,
                                                 const float2* __restrict__ ss,
                                                 float* __restrict__ out,
                                                 int Cin, int CinTot, int cinBase,
                                                 int Cout, int Hin, int accum) {
    __shared__ float sInF[2 * 4356];             // 2 bufs x 66x66
    __shared__ float sWF[2 * 16 * COG];
    const int Hout = Hin >> 1;
    const int tid = threadIdx.x, tx = tid & 31, ty = tid >> 5;
    const int tpr = Hout >> 5;
    const int tX = (blockIdx.x % tpr) * 32, tY = (blockIdx.x / tpr) * 32;
    const int b = blockIdx.y, cog = blockIdx.z * COG;
    const int oy = 2 * tY - 1, ox = 2 * tX - 1;
    const int HH = Hin * Hin;
    const float* inB = in + (size_t)b * Cin * HH;

    constexpr int NS = 18;                        // ceil(4356/256)
    int soff[NS]; float fm[NS];
#pragma unroll
    for (int r = 0; r < NS; r++) {
        int idx = tid + r * 256;
        int iy = idx / 66, ix = idx % 66;
        int gy = oy + iy, gx = ox + ix;
        bool ok = (idx < 4356) && ((unsigned)gy < (unsigned)Hin) &&
                  ((unsigned)gx < (unsigned)Hin);
        soff[r] = ok ? (gy * Hin + gx) : 0;
        fm[r] = ok ? 1.f : 0.f;
    }
    constexpr int NW = (16 * COG + 255) / 256;
    int wgo[NW];
#pragma unroll
    for (int r = 0; r < NW; r++) {
        int widx = tid + r * 256;
        int co = widx % COG, t = widx / COG;
        wgo[r] = ((cog + co) * CinTot + cinBase) * 16 + t;
    }

    float acc[4][COG];
#pragma unroll
    for (int r = 0; r < 4; r++)
#pragma unroll
        for (int c = 0; c < COG; c++) acc[r][c] = 0.f;

    const int steps = Cin;

    {   // stage step 0 -> buf 0
        float pf[NS]; float pw[NW];
        float2 tt = XFORM ? ss[cinBase] : make_float2(1.f, 0.f);
#pragma unroll
        for (int r = 0; r < NS; r++) pf[r] = inB[soff[r]];
#pragma unroll
        for (int r = 0; r < NW; r++)
            pw[r] = (tid + r * 256 < 16 * COG) ? w[wgo[r]] : 0.f;
#pragma unroll
        for (int r = 0; r < NS; r++)
            if (tid + r * 256 < 4356) {
                float v = pf[r];
                if (XFORM) { v = tt.x * v + tt.y; v = (v >= 0.f ? v : 0.2f * v); }
                sInF[tid + r * 256] = v * fm[r];
            }
#pragma unroll
        for (int r = 0; r < NW; r++)
            if (tid + r * 256 < 16 * COG) sWF[tid + r * 256] = pw[r];
    }
    __syncthreads();

    for (int k = 0; k < steps; k++) {
        const int cur = k & 1;
        const bool more = (k + 1) < steps;
        float pf[NS]; float pw[NW]; float2 tt;
        if (more) {
            const int c0n = k + 1;
            const float* p = inB + (size_t)c0n * HH;
            if (XFORM) tt = ss[cinBase + c0n];
#pragma unroll
            for (int r = 0; r < NS; r++) pf[r] = p[soff[r]];
#pragma unroll
            for (int r = 0; r < NW; r++)
                pw[r] = (tid + r * 256 < 16 * COG) ? w[wgo[r] + c0n * 16] : 0.f;
        }
        const float* sI = sInF + cur * 4356;
        const float* sw = sWF + cur * 16 * COG;
#pragma unroll
        for (int dy = 0; dy < 4; dy++)
#pragma unroll
            for (int dx = 0; dx < 4; dx++) {
                const float* basep = sI + (2 * ty + dy) * 66 + 2 * tx + dx;
                float a0 = basep[0];
                float a1 = basep[16 * 66];
                float a2 = basep[32 * 66];
                float a3 = basep[48 * 66];
                const float* wp = sw + (dy * 4 + dx) * COG;
#pragma unroll
                for (int c = 0; c < COG; c++) {
                    float wv = wp[c];
                    acc[0][c] += a0 * wv; acc[1][c] += a1 * wv;
                    acc[2][c] += a2 * wv; acc[3][c] += a3 * wv;
                }
            }
        if (more) {
            const int nb = (cur ^ 1);
#pragma unroll
            for (int r = 0; r < NS; r++)
                if (tid + r * 256 < 4356) {
                    float v = pf[r];
                    if (XFORM) { v = tt.x * v + tt.y; v = (v >= 0.f ? v : 0.2f * v); }
                    sInF[nb * 4356 + tid + r * 256] = v * fm[r];
                }
#pragma unroll
            for (int r = 0; r < NW; r++)
                if (tid + r * 256 < 16 * COG)
                    sWF[nb * 16 * COG + tid + r * 256] = pw[r];
        }
        __syncthreads();
    }

    float* outB = out + ((size_t)b * Cout + cog) * Hout * Hout;
#pragma unroll
    for (int c = 0; c < COG; c++)
#pragma unroll
        for (int r = 0; r < 4; r++) {
            size_t o = (size_t)(c * Hout + (tY + ty + 8 * r)) * Hout + tX + tx;
            if (accum) outB[o] += acc[r][c]; else outB[o] = acc[r][c];
        }
}

// ---------------------------------------------------------------------------
// BN batch stats: per channel partial (sum, sumsq) in FP64 over B=8 x HW
// ---------------------------------------------------------------------------
__global__ __launch_bounds__(256) void stats_k(const float* __restrict__ x,
                                               double2* __restrict__ part,
                                               int C, int hwShift) {
    int c = blockIdx.y, s = blockIdx.x, S = gridDim.x;
    int HW = 1 << hwShift;
    int total = 8 << hwShift;
    int per = total / S;
    int lo = s * per;
    double sum = 0.0, sq = 0.0;
    for (int i = lo + threadIdx.x; i < lo + per; i += 256) {
        int b = i >> hwShift, p = i & (HW - 1);
        double v = (double)x[((size_t)(b * C + c) << hwShift) + p];
        sum += v; sq += v * v;
    }
    __shared__ double s1[256], s2[256];
    s1[threadIdx.x] = sum; s2[threadIdx.x] = sq;
    __syncthreads();
    for (int o = 128; o; o >>= 1) {
        if (threadIdx.x < o) {
            s1[threadIdx.x] += s1[threadIdx.x + o];
            s2[threadIdx.x] += s2[threadIdx.x + o];
        }
        __syncthreads();
    }
    if (threadIdx.x == 0) { part[c * S + s].x = s1[0]; part[c * S + s].y = s2[0]; }
}

__global__ void bnfin_k(const double2* __restrict__ part, int S, int C, double invN,
                        const float* __restrict__ g, const float* __restrict__ bb,
                        float2* __restrict__ ss) {
    int c = threadIdx.x;
    if (c >= C) return;
    double sum = 0.0, sq = 0.0;
    for (int s = 0; s < S; s++) { double2 p = part[c * S + s]; sum += p.x; sq += p.y; }
    double m = sum * invN;
    double v = sq * invN - m * m;
    double sc = (double)g[c] / sqrt(v + 1e-5);
    ss[c] = make_float2((float)sc, (float)((double)bb[c] - m * sc));
}

// ---------------------------------------------------------------------------
// h6raw (8,256,64,64) + BN6 transform+lrelu -> tok (8,4096,256) fp32
// ---------------------------------------------------------------------------
__global__ __launch_bounds__(256) void transp_k(const float* __restrict__ h6,
                                                const float2* __restrict__ ss,
                                                float* __restrict__ tok) {
    __shared__ float sT[32][33];
    int tx = threadIdx.x & 31, ty = threadIdx.x >> 5;
    int n0 = blockIdx.x * 32, d0 = blockIdx.y * 32, b = blockIdx.z;
    const float* hb = h6 + ((size_t)b * 256 + d0) * 4096 + n0;
#pragma unroll
    for (int r = 0; r < 4; r++) {
        int d = ty + 8 * r;
        float2 t = ss[d0 + d];
        sT[d][tx] = lrelu(t.x * hb[d * 4096 + tx] + t.y);
    }
    __syncthreads();
    float* tb = tok + ((size_t)b * 4096 + n0) * 256 + d0;
#pragma unroll
    for (int r = 0; r < 4; r++) {
        int n = ty + 8 * r;
        tb[n * 256 + tx] = sT[tx][n];
    }
}

// ---------------------------------------------------------------------------
// Token stage: gating argmax, selected-expert body slice, ortho, cls MLP.
// ---------------------------------------------------------------------------
__global__ __launch_bounds__(256) void token_k(const float* __restrict__ tok,
                                               const float* __restrict__ wg,
                                               const float* __restrict__ bw,
                                               const float* __restrict__ bb,
                                               const float* __restrict__ ow,
                                               const float* __restrict__ w1,
                                               const float* __restrict__ b1,
                                               const float* __restrict__ w2,
                                               const float* __restrict__ b2,
                                               float* __restrict__ outp) {
    __shared__ float sf[4][256];
    const int tid = threadIdx.x, wave = tid >> 6, l = tid & 63;
    const int t = blockIdx.x * 4 + wave;
    const float4 tv = reinterpret_cast<const float4*>(tok + (size_t)t * 256)[l];
    sf[wave][4 * l + 0] = tv.x; sf[wave][4 * l + 1] = tv.y;
    sf[wave][4 * l + 2] = tv.z; sf[wave][4 * l + 3] = tv.w;

    float lg[12];
#pragma unroll
    for (int e = 0; e < 12; e++) lg[e] = 0.f;
    const float tj[4] = {tv.x, tv.y, tv.z, tv.w};
#pragma unroll
    for (int j = 0; j < 4; j++) {
        const float* wr = wg + (4 * l + j) * 12;
#pragma unroll
        for (int e = 0; e < 12; e++) lg[e] += tj[j] * wr[e];
    }
#pragma unroll
    for (int off = 32; off > 0; off >>= 1) {
#pragma unroll
        for (int e = 0; e < 12; e++) lg[e] += __shfl_xor(lg[e], off);
    }
    int idx = 0; float best = lg[0];
#pragma unroll
    for (int e = 1; e < 12; e++)
        if (lg[e] > best) { best = lg[e]; idx = e; }
    const int cb = idx * 256;

    float f0 = 0.f, f1 = 0.f, f2 = 0.f, f3 = 0.f;
    const float* bwp = bw + cb + 4 * l;
#pragma unroll 4
    for (int d = 0; d < 256; d++) {
        const float td = sf[wave][d];
        const float4 wv = *reinterpret_cast<const float4*>(bwp + (size_t)d * 3072);
        f0 += td * wv.x; f1 += td * wv.y;
        f2 += td * wv.z; f3 += td * wv.w;
    }
    float fj[4] = {f0, f1, f2, f3};
#pragma unroll
    for (int j = 0; j < 4; j++) {
        int jj = cb + 4 * l + j;
        float v = lrelu(fj[j] + bb[jj]);
        v = lrelu(v * ow[jj]);
        sf[wave][4 * l + j] = v;
    }

    float o = 0.f;
    if (l < 32) {
        float h = b1[l];
#pragma unroll 4
        for (int j = 0; j < 256; j++) h += sf[wave][j] * w1[j * 32 + l];
        h = lrelu(h);
        o = h * w2[l];
    }
    o += __shfl_xor(o, 16); o += __shfl_xor(o, 8); o += __shfl_xor(o, 4);
    o += __shfl_xor(o, 2);  o += __shfl_xor(o, 1);
    if (l == 0) outp[t] = o + b2[0];
}

// ---------------------------------------------------------------------------
extern "C" void kernel_launch(void* const* d_in, const int* in_sizes, int n_in,
                              void* d_out, int out_size, void* d_ws, size_t ws_size,
                              hipStream_t stream) {
    const float* x   = (const float*)d_in[0];
    const float* w0  = (const float*)d_in[1];
    const float* b0  = (const float*)d_in[2];
    const float* w1  = (const float*)d_in[3];
    const float* g1  = (const float*)d_in[4];
    const float* be1 = (const float*)d_in[5];
    const float* w2  = (const float*)d_in[6];
    const float* g2  = (const float*)d_in[7];
    const float* be2 = (const float*)d_in[8];
    const float* w3  = (const float*)d_in[9];
    const float* g3  = (const float*)d_in[10];
    const float* be3 = (const float*)d_in[11];
    const float* w4  = (const float*)d_in[12];
    const float* g4  = (const float*)d_in[13];
    const float* be4 = (const float*)d_in[14];
    const float* w5  = (const float*)d_in[15];
    const float* g5  = (const float*)d_in[16];
    const float* be5 = (const float*)d_in[17];
    const float* w6  = (const float*)d_in[18];
    const float* g6  = (const float*)d_in[19];
    const float* be6 = (const float*)d_in[20];
    const float* wg  = (const float*)d_in[21];
    const float* bw  = (const float*)d_in[22];
    const float* bbp = (const float*)d_in[23];
    const float* owp = (const float*)d_in[24];
    const float* cw1 = (const float*)d_in[25];
    const float* cb1 = (const float*)d_in[26];
    const float* cw2 = (const float*)d_in[27];
    const float* cb2 = (const float*)d_in[28];

    char* W = (char*)d_ws;
    float2* ssb = (float2*)W;
    float2* ss1 = ssb;
    float2* ss2 = ssb + 64;
    float2* ss3 = ssb + 192;
    float2* ss4 = ssb + 320;
    float2* ss5 = ssb + 576;
    float2* ss6 = ssb + 832;
    double2* part = (double2*)(W + 16384);

    char* A = W + 262144;
    char* B = A + 67108864;
    float* h0  = (float*)A;
    float* h1  = (float*)B;
    float* h2  = (float*)A;
    float* h3  = (float*)B;
    float* h4  = (float*)A;
    float* h5  = (float*)(A + 33554432);
    float* h6  = (float*)B;
    float* tok = (float*)A;

    // conv0+conv1 in two cin-halves (h0 fp32 within 64MiB)
    conv0_k<<<dim3(64, 8, 2), 256, 0, stream>>>(x, w0, b0, h0, 0);
    conv4x4_k<8, false><<<dim3(16, 8, 8), 256, 0, stream>>>(
        h0, w1, nullptr, h1, 32, 64, 0, 64, 256, 0);
    conv0_k<<<dim3(64, 8, 2), 256, 0, stream>>>(x, w0, b0, h0, 32);
    conv4x4_k<8, false><<<dim3(16, 8, 8), 256, 0, stream>>>(
        h0, w1, nullptr, h1, 32, 64, 32, 64, 256, 1);
    stats_k<<<dim3(32, 64), 256, 0, stream>>>(h1, part, 64, 14);
    bnfin_k<<<1, 256, 0, stream>>>(part, 32, 64, 1.0 / 131072.0, g1, be1, ss1);
    // conv2 3x3: h1 (+bn1+lrelu) -> h2
    conv3x3_k<16><<<dim3(16, 8, 8), 256, 0, stream>>>(h1, w2, ss1, h2, 64, 128, 128);
    stats_k<<<dim3(32, 128), 256, 0, stream>>>(h2, part, 128, 14);
    bnfin_k<<<1, 256, 0, stream>>>(part, 32, 128, 1.0 / 131072.0, g2, be2, ss2);
    // conv3 4x4 s2: h2 (+bn2+lrelu) -> h3
    conv4x4_k<8, true><<<dim3(4, 8, 16), 256, 0, stream>>>(
        h2, w3, ss2, h3, 128, 128, 0, 128, 128, 0);
    stats_k<<<dim3(32, 128), 256, 0, stream>>>(h3, part, 128, 12);
    bnfin_k<<<1, 256, 0, stream>>>(part, 32, 128, 1.0 / 32768.0, g3, be3, ss3);
    // conv4 3x3: h3 (+bn3+lrelu) -> h4
    conv3x3_k<8><<<dim3(4, 8, 32), 256, 0, stream>>>(h3, w4, ss3, h4, 128, 256, 64);
    stats_k<<<dim3(32, 256), 256, 0, stream>>>(h4, part, 256, 12);
    bnfin_k<<<1, 256, 0, stream>>>(part, 32, 256, 1.0 / 32768.0, g4, be4, ss4);
    // conv5 3x3: h4 (+bn4+lrelu) -> h5
    conv3x3_k<8><<<dim3(4, 8, 32), 256, 0, stream>>>(h4, w5, ss4, h5, 256, 256, 64);
    stats_k<<<dim3(32, 256), 256, 0, stream>>>(h5, part, 256, 12);
    bnfin_k<<<1, 256, 0, stream>>>(part, 32, 256, 1.0 / 32768.0, g5, be5, ss5);
    // conv6 3x3: h5 (+bn5+lrelu) -> h6
    conv3x3_k<8><<<dim3(4, 8, 32), 256, 0, stream>>>(h5, w6, ss5, h6, 256, 256, 64);
    stats_k<<<dim3(32, 256), 256, 0, stream>>>(h6, part, 256, 12);
    bnfin_k<<<1, 256, 0, stream>>>(part, 32, 256, 1.0 / 32768.0, g6, be6, ss6);
    // transpose + BN6 + lrelu -> tok
    transp_k<<<dim3(128, 8, 8), 256, 0, stream>>>(h6, ss6, tok);
    // token stage -> out fp32 (8,4096,1)
    token_k<<<8192, 256, 0, stream>>>(tok, wg, bw, bbp, owp, cw1, cb1, cw2, cb2,
                                      (float*)d_out);
}